// Round 10
// baseline (220.546 us; speedup 1.0000x reference)
//
#include <hip/hip_runtime.h>
#include <cstdint>
#include <cstddef>

// Problem constants (match reference file)
#define BB 4
#define MM 8192
#define NN 6890
#define NSEG 64
#define SEGN 108          // ceil(6890/64); last segment has 86
#define G 16              // tournament group size
#define GMAX 7            // groups per segment (compile-time; pads inert)
#define GSTRIDE 17        // group stride in float4 slots (bank-spread pad)
#define CHUNKS 8          // MM / MQ
#define MQ 1024           // queries per nn block (TPB * QT)
#define QT 4              // queries per thread
#define TPB 256
#define NQ (BB * MM)      // 32768 queries
#define NFBLK 512         // finalize blocks (seg-split)

static constexpr float MIN_T2 = 0.005f * 0.005f;   // MIN_DIST_THRESH^2

// ws layout (bytes):
//   [0, 16777216)            u64 partials[NSEG][NQ]  (d2_bits<<32 | idx)
//   [16777216, +2048)        float bsum[512]
//   [16779264, +2048)        int   bmatch[512]
#define OFF_BSUM   16777216
#define OFF_BMATCH (16777216 + 2048)

static __device__ __forceinline__ unsigned long long u64min(
    unsigned long long a, unsigned long long b) { return a < b ? a : b; }

// Kernel 1: per-(batch, m-chunk, n-segment) NN, group tournament.
// == R9 structure (best measured: 103.4us; 2048 blocks = 8 blocks/CU x
// 4 waves = 8 waves/SIMD) with ONE nn change: the g-loop bound is now the
// COMPILE-TIME constant GMAX=7 (was runtime ngroups), enabling full unroll
// and cross-group load/compute pipelining; __launch_bounds__(256,8) pins
// the 64-VGPR ceiling so the unroll cannot trade occupancy (R1's QT=4
// variant used 32 VGPR -- ample headroom). Pads (0,0,0,+inf) are inert:
// e=+inf never wins strict <, a pad-only group is never selected, and the
// all-invalid corner (bd=inf -> near=false -> contrib=0) is unchanged.
// Tiebreaks identical to R9 (verified absmax 0.0).
__global__ __launch_bounds__(TPB, 8) void nn_kernel(
    const float* __restrict__ cloth, const float* __restrict__ vt,
    const int* __restrict__ valid, unsigned long long* __restrict__ partials)
{
    __shared__ float4 lds[GMAX * GSTRIDE];   // 119 float4 = 1904 B
    int bid   = blockIdx.x;            // 2048 blocks = 8/CU
    int seg   = bid & (NSEG - 1);
    int chunk = (bid >> 6) & (CHUNKS - 1);
    int b     = bid >> 9;
    int n0    = seg * SEGN;
    int segn  = (NN - n0 < SEGN) ? (NN - n0) : SEGN;

    // fused candidate prep: (-2x,-2y,-2z, s2 or +inf if invalid); pads inert
    if (threadIdx.x < GMAX * G) {
        float4 v = make_float4(0.0f, 0.0f, 0.0f, __builtin_inff());
        if (threadIdx.x < segn) {
            int n = n0 + threadIdx.x;
            const float* p = vt + ((size_t)b * NN + n) * 3;
            float x = p[0], y = p[1], z = p[2];
            float s2 = x * x + y * y + z * z;
            if (valid[b * NN + n] <= 0) s2 = __builtin_inff();
            v = make_float4(-2.0f * x, -2.0f * y, -2.0f * z, s2);
        }
        int slot = (threadIdx.x >> 4) * GSTRIDE + (threadIdx.x & (G - 1));
        lds[slot] = v;
    }

    float qx[QT], qy[QT], qz[QT], qc2[QT], bd[QT];
    int gb[QT];
    int m0 = chunk * MQ + threadIdx.x;
#pragma unroll
    for (int j = 0; j < QT; j++) {
        int m = m0 + j * TPB;
        const float* p = cloth + ((size_t)b * MM + m) * 3;
        float x = p[0], y = p[1], z = p[2];
        qx[j] = x; qy[j] = y; qz[j] = z;
        qc2[j] = x * x + y * y + z * z;
        bd[j] = __builtin_inff();
        gb[j] = 0;
    }
    __syncthreads();

    // Hot loop: UNFILTERED value-min in shifted space e = s2 - 2 c.s,
    // group tournament, STATIC bounds -> fully unrollable/pipelinable.
#pragma unroll
    for (int g = 0; g < GMAX; g++) {
        int base = g * GSTRIDE;
        float gm[QT];
#pragma unroll
        for (int j = 0; j < QT; j++) gm[j] = __builtin_inff();
#pragma unroll
        for (int t = 0; t < G; t += 2) {
            float4 c0 = lds[base + t];
            float4 c1 = lds[base + t + 1];
#pragma unroll
            for (int j = 0; j < QT; j++) {
                float e0 = fmaf(c0.x, qx[j],
                           fmaf(c0.y, qy[j], fmaf(c0.z, qz[j], c0.w)));
                float e1 = fmaf(c1.x, qx[j],
                           fmaf(c1.y, qy[j], fmaf(c1.z, qz[j], c1.w)));
                gm[j] = fminf(fminf(e0, e1), gm[j]);
            }
        }
#pragma unroll
        for (int j = 0; j < QT; j++) {
            bool ok = gm[j] < bd[j];
            bd[j] = ok ? gm[j] : bd[j];
            gb[j] = ok ? g : gb[j];
        }
    }

    // index recovery: equality rescan of the winning group, batches of 4
    // candidates staged in NAMED float4s (no arrays -> no scratch).
    // Batches high->low, within-batch high->low: lowest matching t
    // assigned last -> lowest-index tiebreak (verified absmax 0.0 R7-R9).
    int bi[QT];
#pragma unroll
    for (int j = 0; j < QT; j++) {
        int base = gb[j] * GSTRIDE;
        float tgt = bd[j];
        int mloc = G;                    // G = not found (unreachable)
#pragma unroll
        for (int tb = G - 4; tb >= 0; tb -= 4) {
            float4 ca = lds[base + tb + 3];
            float4 cb = lds[base + tb + 2];
            float4 cc = lds[base + tb + 1];
            float4 cd = lds[base + tb + 0];
            float ea = fmaf(ca.x, qx[j], fmaf(ca.y, qy[j], fmaf(ca.z, qz[j], ca.w)));
            float eb = fmaf(cb.x, qx[j], fmaf(cb.y, qy[j], fmaf(cb.z, qz[j], cb.w)));
            float ec = fmaf(cc.x, qx[j], fmaf(cc.y, qy[j], fmaf(cc.z, qz[j], cc.w)));
            float ed = fmaf(cd.x, qx[j], fmaf(cd.y, qy[j], fmaf(cd.z, qz[j], cd.w)));
            mloc = (ea == tgt) ? (tb + 3) : mloc;
            mloc = (eb == tgt) ? (tb + 2) : mloc;
            mloc = (ec == tgt) ? (tb + 1) : mloc;
            mloc = (ed == tgt) ? (tb + 0) : mloc;
        }
        int gi = n0 + (gb[j] << 4) + ((mloc < G) ? mloc : 0);
        bi[j] = (gi > NN - 1) ? (NN - 1) : gi;   // pad corner clamp
    }

    // rare fallback: unfiltered min is a too-close candidate -> rescan this
    // segment with the full filter (if the min passes, all candidates do).
#pragma unroll
    for (int j = 0; j < QT; j++) {
        float tmin = MIN_T2 - qc2[j];
        if (bd[j] < tmin) {
            float fb = __builtin_inff(); int fi = 0;
            for (int i = 0; i < segn; i++) {
                float4 c = lds[(i >> 4) * GSTRIDE + (i & (G - 1))];
                float e = fmaf(c.x, qx[j], fmaf(c.y, qy[j], fmaf(c.z, qz[j], c.w)));
                bool ok = (e >= tmin) && (e < fb);
                fb = ok ? e : fb;
                fi = ok ? (n0 + i) : fi;
            }
            bd[j] = fb; bi[j] = fi;
        }
    }

    // coalesced partial store: d2 = e + qc2 >= MIN_T2 > 0 (or +inf), so
    // float bits order correctly as unsigned; low 32 bits = idx tiebreak.
#pragma unroll
    for (int j = 0; j < QT; j++) {
        int q = b * MM + m0 + j * TPB;
        float d2 = bd[j] + qc2[j];
        unsigned long long key =
            ((unsigned long long)__float_as_uint(d2) << 32) | (unsigned)bi[j];
        partials[(size_t)seg * NQ + q] = key;
    }
}

// Kernel 2: per-query u64-min, SEG-SPLIT for occupancy: R9's 256x128 grid
// was 2 waves/CU doing 64 latency-bound loads/thread. Now 512 blocks x
// 128 thr: each block covers 64 queries; wave 0 takes segs 0-31, wave 1
// segs 32-63; halves combined via LDS; wave 0 finishes (gather, contrib,
// wave-reduce, one store). 4 waves/CU, half the serial loads per thread.
__global__ __launch_bounds__(128) void finalize_kernel(
    const unsigned long long* __restrict__ partials,
    const int* __restrict__ smpl_idx, const float* __restrict__ sdf,
    const int* __restrict__ cloth_idx, const float* __restrict__ sdf_thresh,
    const float* __restrict__ dist_thresh,
    float* __restrict__ bsum, int* __restrict__ bmatch)
{
    int lq   = threadIdx.x & 63;
    int half = threadIdx.x >> 6;              // 0 or 1 (wave-uniform)
    int q = blockIdx.x * 64 + lq;             // 512 blocks x 64 queries
    int b = q >> 13;
    int s0 = half * 32;
    unsigned long long mm[8];
#pragma unroll
    for (int k = 0; k < 8; k++) mm[k] = ~0ULL;
#pragma unroll
    for (int s = 0; s < 32; s += 8) {
#pragma unroll
        for (int k = 0; k < 8; k++)
            mm[k] = u64min(mm[k], partials[(size_t)(s0 + s + k) * NQ + q]);
    }
    unsigned long long key =
        u64min(u64min(u64min(mm[0], mm[1]), u64min(mm[2], mm[3])),
               u64min(u64min(mm[4], mm[5]), u64min(mm[6], mm[7])));

    __shared__ unsigned long long lk[64];
    if (half == 1) lk[lq] = key;
    __syncthreads();
    if (half == 0) {
        key = u64min(key, lk[lq]);

        float d2  = __uint_as_float((unsigned)(key >> 32));
        int   idx = (int)(unsigned)(key & 0xFFFFFFFFu);
        int target = smpl_idx[b * NN + idx];
        int ci0 = cloth_idx[0], ci1 = cloth_idx[1];
        bool match = (target == ci0) || (target == ci1);
        bool near_ = sqrtf(d2) < dist_thresh[0];     // inf -> false
        float s = sdf[q];
        float contrib = near_ ? (match ? fabsf(s) : fabsf(s - sdf_thresh[0]))
                              : 0.0f;
        int mt = match ? 1 : 0;

        for (int off = 32; off > 0; off >>= 1) {
            contrib += __shfl_down(contrib, off, 64);
            mt      |= __shfl_down(mt, off, 64);
        }
        if (lq == 0) {
            bsum[blockIdx.x]   = contrib;
            bmatch[blockIdx.x] = mt;
        }
    }
}

// Kernel 3: 512 block-partials -> 4 batch losses. Wave w reduces partials
// [64w,64w+64) (all one batch: batch = blk>>7 = w>>1); pairs of wave sums
// combine via LDS.
__global__ __launch_bounds__(512) void reduce_kernel(
    const float* __restrict__ bs, const int* __restrict__ bm,
    float* __restrict__ out)
{
    int t = threadIdx.x;          // 0..511
    float s = bs[t];
    int   m = bm[t];
    for (int off = 32; off > 0; off >>= 1) {
        s += __shfl_down(s, off, 64);
        m |= __shfl_down(m, off, 64);
    }
    __shared__ float wsu[8];
    __shared__ int   wma[8];
    int w = t >> 6;
    if ((t & 63) == 0) { wsu[w] = s; wma[w] = m; }
    __syncthreads();
    if (t < BB) {
        float sb = wsu[2 * t] + wsu[2 * t + 1];
        int   mb = wma[2 * t] | wma[2 * t + 1];
        out[t] = sb * (1.0f / (float)MM) * (mb ? 1.0f : 0.0f);
    }
}

extern "C" void kernel_launch(void* const* d_in, const int* in_sizes, int n_in,
                              void* d_out, int out_size, void* d_ws, size_t ws_size,
                              hipStream_t stream)
{
    const float* sdf         = (const float*)d_in[0];
    const float* cloth       = (const float*)d_in[1];
    const int*   smpl_idx    = (const int*)d_in[2];
    const int*   valid       = (const int*)d_in[3];
    const int*   cloth_idx   = (const int*)d_in[4];
    const float* sdf_thresh  = (const float*)d_in[5];
    const float* dist_thresh = (const float*)d_in[6];
    const float* vt          = (const float*)d_in[7];

    char* ws = (char*)d_ws;
    unsigned long long* partials = (unsigned long long*)ws;
    float* bsum   = (float*)(ws + OFF_BSUM);
    int*   bmatch = (int*)(ws + OFF_BMATCH);

    nn_kernel<<<BB * CHUNKS * NSEG, TPB, 0, stream>>>(cloth, vt, valid, partials);
    finalize_kernel<<<NFBLK, 128, 0, stream>>>(
        partials, smpl_idx, sdf, cloth_idx, sdf_thresh, dist_thresh,
        bsum, bmatch);
    reduce_kernel<<<1, 512, 0, stream>>>(bsum, bmatch, (float*)d_out);
}

// Round 11
// 103.673 us; speedup vs baseline: 2.1273x; 2.1273x over previous
//
#include <hip/hip_runtime.h>
#include <cstdint>
#include <cstddef>

// Problem constants (match reference file)
#define BB 4
#define MM 8192
#define NN 6890
#define NSEG 64
#define SEGN 108          // ceil(6890/64); last segment has 86
#define G 16              // tournament group size
#define GMAX 7            // max groups per segment
#define GSTRIDE 17        // group stride in float4 slots (bank-spread pad)
#define CHUNKS 8          // MM / MQ
#define MQ 1024           // queries per nn block (TPB * QT)
#define QT 4              // queries per thread
#define TPB 256
#define NQ (BB * MM)      // 32768 queries
#define NFBLK 512         // finalize blocks (seg-split)

static constexpr float MIN_T2 = 0.005f * 0.005f;   // MIN_DIST_THRESH^2

// ws layout (bytes):
//   [0, 16777216)            u64 partials[NSEG][NQ]  (d2_bits<<32 | idx)
//   [16777216, +2048)        float bsum[512]
//   [16779264, +2048)        int   bmatch[512]
#define OFF_BSUM   16777216
#define OFF_BMATCH (16777216 + 2048)

static __device__ __forceinline__ unsigned long long u64min(
    unsigned long long a, unsigned long long b) { return a < b ? a : b; }

// Kernel 1: per-(batch, m-chunk, n-segment) NN, group tournament.
// == EXACT R9 nn (best measured: 103.4us total; 2048 blocks = 8 blocks/CU
// x 4 waves = 8 waves/SIMD, VGPR ~50, no spill, conflicts ~0) ==
// R10 post-mortem: static GMAX unroll + __launch_bounds__(256,8) forced
// the allocator under the unrolled pipeline's live-range -> scratch spill
// (FETCH 172MB / WRITE 354MB, nn 144-178us). Second confirmation (after
// R6) that pushing the allocator on this kernel converts to scratch, not
// speed. Runtime g-loop + default bounds is the stable optimum; DO NOT
// re-unroll or re-pin.
__global__ __launch_bounds__(TPB) void nn_kernel(
    const float* __restrict__ cloth, const float* __restrict__ vt,
    const int* __restrict__ valid, unsigned long long* __restrict__ partials)
{
    __shared__ float4 lds[GMAX * GSTRIDE];   // 119 float4 = 1904 B
    int bid   = blockIdx.x;            // 2048 blocks = 8/CU
    int seg   = bid & (NSEG - 1);
    int chunk = (bid >> 6) & (CHUNKS - 1);
    int b     = bid >> 9;
    int n0    = seg * SEGN;
    int segn  = (NN - n0 < SEGN) ? (NN - n0) : SEGN;
    int ngroups = (segn + G - 1) / G;
    int npad    = ngroups * G;

    // fused candidate prep: (-2x,-2y,-2z, s2 or +inf if invalid); pads inert
    if (threadIdx.x < npad) {
        float4 v = make_float4(0.0f, 0.0f, 0.0f, __builtin_inff());
        if (threadIdx.x < segn) {
            int n = n0 + threadIdx.x;
            const float* p = vt + ((size_t)b * NN + n) * 3;
            float x = p[0], y = p[1], z = p[2];
            float s2 = x * x + y * y + z * z;
            if (valid[b * NN + n] <= 0) s2 = __builtin_inff();
            v = make_float4(-2.0f * x, -2.0f * y, -2.0f * z, s2);
        }
        int slot = (threadIdx.x >> 4) * GSTRIDE + (threadIdx.x & (G - 1));
        lds[slot] = v;
    }

    float qx[QT], qy[QT], qz[QT], qc2[QT], bd[QT];
    int gb[QT];
    int m0 = chunk * MQ + threadIdx.x;
#pragma unroll
    for (int j = 0; j < QT; j++) {
        int m = m0 + j * TPB;
        const float* p = cloth + ((size_t)b * MM + m) * 3;
        float x = p[0], y = p[1], z = p[2];
        qx[j] = x; qy[j] = y; qz[j] = z;
        qc2[j] = x * x + y * y + z * z;
        bd[j] = __builtin_inff();
        gb[j] = 0;
    }
    __syncthreads();

    // Hot loop: UNFILTERED value-min in shifted space e = s2 - 2 c.s,
    // group tournament, candidates in pairs -> min3 fold.
    for (int g = 0; g < ngroups; g++) {
        int base = g * GSTRIDE;
        float gm[QT];
#pragma unroll
        for (int j = 0; j < QT; j++) gm[j] = __builtin_inff();
#pragma unroll
        for (int t = 0; t < G; t += 2) {
            float4 c0 = lds[base + t];
            float4 c1 = lds[base + t + 1];
#pragma unroll
            for (int j = 0; j < QT; j++) {
                float e0 = fmaf(c0.x, qx[j],
                           fmaf(c0.y, qy[j], fmaf(c0.z, qz[j], c0.w)));
                float e1 = fmaf(c1.x, qx[j],
                           fmaf(c1.y, qy[j], fmaf(c1.z, qz[j], c1.w)));
                gm[j] = fminf(fminf(e0, e1), gm[j]);
            }
        }
#pragma unroll
        for (int j = 0; j < QT; j++) {
            bool ok = gm[j] < bd[j];
            bd[j] = ok ? gm[j] : bd[j];
            gb[j] = ok ? g : gb[j];
        }
    }

    // index recovery: equality rescan of the winning group, batches of 4
    // candidates staged in NAMED float4s (no arrays -> no scratch).
    // Batches high->low, within-batch high->low: lowest matching t
    // assigned last -> lowest-index tiebreak (verified absmax 0.0 R7-R10).
    int bi[QT];
#pragma unroll
    for (int j = 0; j < QT; j++) {
        int base = gb[j] * GSTRIDE;
        float tgt = bd[j];
        int mloc = G;                    // G = not found (unreachable)
#pragma unroll
        for (int tb = G - 4; tb >= 0; tb -= 4) {
            float4 ca = lds[base + tb + 3];
            float4 cb = lds[base + tb + 2];
            float4 cc = lds[base + tb + 1];
            float4 cd = lds[base + tb + 0];
            float ea = fmaf(ca.x, qx[j], fmaf(ca.y, qy[j], fmaf(ca.z, qz[j], ca.w)));
            float eb = fmaf(cb.x, qx[j], fmaf(cb.y, qy[j], fmaf(cb.z, qz[j], cb.w)));
            float ec = fmaf(cc.x, qx[j], fmaf(cc.y, qy[j], fmaf(cc.z, qz[j], cc.w)));
            float ed = fmaf(cd.x, qx[j], fmaf(cd.y, qy[j], fmaf(cd.z, qz[j], cd.w)));
            mloc = (ea == tgt) ? (tb + 3) : mloc;
            mloc = (eb == tgt) ? (tb + 2) : mloc;
            mloc = (ec == tgt) ? (tb + 1) : mloc;
            mloc = (ed == tgt) ? (tb + 0) : mloc;
        }
        int gi = n0 + (gb[j] << 4) + ((mloc < G) ? mloc : 0);
        bi[j] = (gi > NN - 1) ? (NN - 1) : gi;   // pad corner clamp
    }

    // rare fallback: unfiltered min is a too-close candidate -> rescan this
    // segment with the full filter (if the min passes, all candidates do).
#pragma unroll
    for (int j = 0; j < QT; j++) {
        float tmin = MIN_T2 - qc2[j];
        if (bd[j] < tmin) {
            float fb = __builtin_inff(); int fi = 0;
            for (int i = 0; i < segn; i++) {
                float4 c = lds[(i >> 4) * GSTRIDE + (i & (G - 1))];
                float e = fmaf(c.x, qx[j], fmaf(c.y, qy[j], fmaf(c.z, qz[j], c.w)));
                bool ok = (e >= tmin) && (e < fb);
                fb = ok ? e : fb;
                fi = ok ? (n0 + i) : fi;
            }
            bd[j] = fb; bi[j] = fi;
        }
    }

    // coalesced partial store: d2 = e + qc2 >= MIN_T2 > 0 (or +inf), so
    // float bits order correctly as unsigned; low 32 bits = idx tiebreak.
#pragma unroll
    for (int j = 0; j < QT; j++) {
        int q = b * MM + m0 + j * TPB;
        float d2 = bd[j] + qc2[j];
        unsigned long long key =
            ((unsigned long long)__float_as_uint(d2) << 32) | (unsigned)bi[j];
        partials[(size_t)seg * NQ + q] = key;
    }
}

// Kernel 2: per-query u64-min, SEG-SPLIT for occupancy (R10-verified
// correct, absmax 0.0): 512 blocks x 128 thr; each block covers 64
// queries; wave 0 takes segs 0-31, wave 1 segs 32-63; halves combined via
// LDS; wave 0 finishes. 4 waves/CU with half the serialized latency-loads
// per thread vs the 256x128 version.
__global__ __launch_bounds__(128) void finalize_kernel(
    const unsigned long long* __restrict__ partials,
    const int* __restrict__ smpl_idx, const float* __restrict__ sdf,
    const int* __restrict__ cloth_idx, const float* __restrict__ sdf_thresh,
    const float* __restrict__ dist_thresh,
    float* __restrict__ bsum, int* __restrict__ bmatch)
{
    int lq   = threadIdx.x & 63;
    int half = threadIdx.x >> 6;              // 0 or 1 (wave-uniform)
    int q = blockIdx.x * 64 + lq;             // 512 blocks x 64 queries
    int b = q >> 13;
    int s0 = half * 32;
    unsigned long long mm[8];
#pragma unroll
    for (int k = 0; k < 8; k++) mm[k] = ~0ULL;
#pragma unroll
    for (int s = 0; s < 32; s += 8) {
#pragma unroll
        for (int k = 0; k < 8; k++)
            mm[k] = u64min(mm[k], partials[(size_t)(s0 + s + k) * NQ + q]);
    }
    unsigned long long key =
        u64min(u64min(u64min(mm[0], mm[1]), u64min(mm[2], mm[3])),
               u64min(u64min(mm[4], mm[5]), u64min(mm[6], mm[7])));

    __shared__ unsigned long long lk[64];
    if (half == 1) lk[lq] = key;
    __syncthreads();
    if (half == 0) {
        key = u64min(key, lk[lq]);

        float d2  = __uint_as_float((unsigned)(key >> 32));
        int   idx = (int)(unsigned)(key & 0xFFFFFFFFu);
        int target = smpl_idx[b * NN + idx];
        int ci0 = cloth_idx[0], ci1 = cloth_idx[1];
        bool match = (target == ci0) || (target == ci1);
        bool near_ = sqrtf(d2) < dist_thresh[0];     // inf -> false
        float s = sdf[q];
        float contrib = near_ ? (match ? fabsf(s) : fabsf(s - sdf_thresh[0]))
                              : 0.0f;
        int mt = match ? 1 : 0;

        for (int off = 32; off > 0; off >>= 1) {
            contrib += __shfl_down(contrib, off, 64);
            mt      |= __shfl_down(mt, off, 64);
        }
        if (lq == 0) {
            bsum[blockIdx.x]   = contrib;
            bmatch[blockIdx.x] = mt;
        }
    }
}

// Kernel 3: 512 block-partials -> 4 batch losses. Wave w reduces partials
// [64w,64w+64) (all one batch: batch = blk>>7 = w>>1); pairs of wave sums
// combine via LDS.
__global__ __launch_bounds__(512) void reduce_kernel(
    const float* __restrict__ bs, const int* __restrict__ bm,
    float* __restrict__ out)
{
    int t = threadIdx.x;          // 0..511
    float s = bs[t];
    int   m = bm[t];
    for (int off = 32; off > 0; off >>= 1) {
        s += __shfl_down(s, off, 64);
        m |= __shfl_down(m, off, 64);
    }
    __shared__ float wsu[8];
    __shared__ int   wma[8];
    int w = t >> 6;
    if ((t & 63) == 0) { wsu[w] = s; wma[w] = m; }
    __syncthreads();
    if (t < BB) {
        float sb = wsu[2 * t] + wsu[2 * t + 1];
        int   mb = wma[2 * t] | wma[2 * t + 1];
        out[t] = sb * (1.0f / (float)MM) * (mb ? 1.0f : 0.0f);
    }
}

extern "C" void kernel_launch(void* const* d_in, const int* in_sizes, int n_in,
                              void* d_out, int out_size, void* d_ws, size_t ws_size,
                              hipStream_t stream)
{
    const float* sdf         = (const float*)d_in[0];
    const float* cloth       = (const float*)d_in[1];
    const int*   smpl_idx    = (const int*)d_in[2];
    const int*   valid       = (const int*)d_in[3];
    const int*   cloth_idx   = (const int*)d_in[4];
    const float* sdf_thresh  = (const float*)d_in[5];
    const float* dist_thresh = (const float*)d_in[6];
    const float* vt          = (const float*)d_in[7];

    char* ws = (char*)d_ws;
    unsigned long long* partials = (unsigned long long*)ws;
    float* bsum   = (float*)(ws + OFF_BSUM);
    int*   bmatch = (int*)(ws + OFF_BMATCH);

    nn_kernel<<<BB * CHUNKS * NSEG, TPB, 0, stream>>>(cloth, vt, valid, partials);
    finalize_kernel<<<NFBLK, 128, 0, stream>>>(
        partials, smpl_idx, sdf, cloth_idx, sdf_thresh, dist_thresh,
        bsum, bmatch);
    reduce_kernel<<<1, 512, 0, stream>>>(bsum, bmatch, (float*)d_out);
}

// Round 12
// 99.916 us; speedup vs baseline: 2.2073x; 1.0376x over previous
//
#include <hip/hip_runtime.h>
#include <cstdint>
#include <cstddef>

// Problem constants (match reference file)
#define BB 4
#define MM 8192
#define NN 6890
#define NSEG 64
#define SEGN 108          // ceil(6890/64); last segment has 86
#define G 16              // tournament group size
#define GMAX 7            // max groups per segment
#define GSTRIDE 17        // group stride in float4 slots
#define CHUNKS 8          // MM / MQ
#define MQ 1024           // queries per nn block (TPB * QT)
#define QT 4              // queries per thread
#define TPB 256
#define NQ (BB * MM)      // 32768 queries
#define NFBLK 512         // finalize blocks (seg-split)

static constexpr float MIN_T2 = 0.005f * 0.005f;   // MIN_DIST_THRESH^2

// ws layout (bytes):
//   [0, 16777216)            u64 partials[NSEG][NQ]
//       key = emap(e)<<32 | seg<<15 | loc<<8 | flag<<7
//       e-space ordering == d2-space ordering per query (d2 = e + qc2,
//       qc2 query-constant); emap is the standard order-preserving
//       float->u32 flip (handles negative e). low bits order seg->loc ->
//       lowest-index-region tiebreak on equal e.
//   [16777216, +2048)        float bsum[512]
//   [16779264, +2048)        int   bmatch[512]
#define OFF_BSUM   16777216
#define OFF_BMATCH (16777216 + 2048)

static __device__ __forceinline__ unsigned long long u64min(
    unsigned long long a, unsigned long long b) { return a < b ? a : b; }

// Shared helpers: IDENTICAL expressions in nn (scan) and finalize
// (recovery) so recomputed e is bit-exact (same compiler, same source,
// same types -> same instruction selection).
static __device__ __forceinline__ float4 prep_cand(
    const float* __restrict__ vtb, const int* __restrict__ validb, int n)
{
    const float* p = vtb + (size_t)n * 3;
    float x = p[0], y = p[1], z = p[2];
    float s2 = x * x + y * y + z * z;
    if (validb[n] <= 0) s2 = __builtin_inff();
    return make_float4(-2.0f * x, -2.0f * y, -2.0f * z, s2);
}
static __device__ __forceinline__ float edot(float4 c, float qx, float qy,
                                             float qz)
{
    return fmaf(c.x, qx, fmaf(c.y, qy, fmaf(c.z, qz, c.w)));
}
// order-preserving float->u32 (monotone over all floats incl. negatives)
static __device__ __forceinline__ unsigned emap(float e) {
    unsigned b = __float_as_uint(e);
    return ((int)b < 0) ? ~b : (b | 0x80000000u);
}

// Kernel 1: per-(batch, m-chunk, n-segment) NN, group tournament.
// == R9/R11 structure (best measured 103.4us; 2048 blocks = 8 blocks/CU x
// 4 waves = 8 waves/SIMD, no spill) with DEFERRED RECOVERY ==
// R11 arithmetic: nn is LDS-PIPE-bound (176 ds_read_b128/wave x 12cy x
// 32 waves/CU = 28us of nn's ~32us; VALU only 10.5us). 64 of the 176 are
// the per-segment index-recovery rescan -- wasteful, since only ONE of 64
// segments wins per query. R12: nn stores only (e, seg, group-base);
// finalize recovers the index ONCE per query. Removes 36% of nn's LDS
// instructions. Fallback (too-close; rare) still resolves its exact index
// in nn and marks flag=1.
__global__ __launch_bounds__(TPB) void nn_kernel(
    const float* __restrict__ cloth, const float* __restrict__ vt,
    const int* __restrict__ valid, unsigned long long* __restrict__ partials)
{
    __shared__ float4 lds[GMAX * GSTRIDE];   // 119 float4 = 1904 B
    int bid   = blockIdx.x;            // 2048 blocks = 8/CU
    int seg   = bid & (NSEG - 1);
    int chunk = (bid >> 6) & (CHUNKS - 1);
    int b     = bid >> 9;
    int n0    = seg * SEGN;
    int segn  = (NN - n0 < SEGN) ? (NN - n0) : SEGN;
    int ngroups = (segn + G - 1) / G;
    int npad    = ngroups * G;

    const float* vtb    = vt + (size_t)b * NN * 3;
    const int*   validb = valid + b * NN;

    // fused candidate prep (shared helper); pads (0,0,0,+inf) inert
    if (threadIdx.x < npad) {
        float4 v = make_float4(0.0f, 0.0f, 0.0f, __builtin_inff());
        if (threadIdx.x < segn) v = prep_cand(vtb, validb, n0 + threadIdx.x);
        int slot = (threadIdx.x >> 4) * GSTRIDE + (threadIdx.x & (G - 1));
        lds[slot] = v;
    }

    float qx[QT], qy[QT], qz[QT], qc2[QT], bd[QT];
    int gb[QT];
    int m0 = chunk * MQ + threadIdx.x;
#pragma unroll
    for (int j = 0; j < QT; j++) {
        int m = m0 + j * TPB;
        const float* p = cloth + ((size_t)b * MM + m) * 3;
        float x = p[0], y = p[1], z = p[2];
        qx[j] = x; qy[j] = y; qz[j] = z;
        qc2[j] = x * x + y * y + z * z;
        bd[j] = __builtin_inff();
        gb[j] = 0;
    }
    __syncthreads();

    // Hot loop: UNFILTERED value-min in shifted space e = s2 - 2 c.s,
    // group tournament, candidates in pairs -> min3 fold.
    for (int g = 0; g < ngroups; g++) {
        int base = g * GSTRIDE;
        float gm[QT];
#pragma unroll
        for (int j = 0; j < QT; j++) gm[j] = __builtin_inff();
#pragma unroll
        for (int t = 0; t < G; t += 2) {
            float4 c0 = lds[base + t];
            float4 c1 = lds[base + t + 1];
#pragma unroll
            for (int j = 0; j < QT; j++) {
                float e0 = edot(c0, qx[j], qy[j], qz[j]);
                float e1 = edot(c1, qx[j], qy[j], qz[j]);
                gm[j] = fminf(fminf(e0, e1), gm[j]);
            }
        }
#pragma unroll
        for (int j = 0; j < QT; j++) {
            bool ok = gm[j] < bd[j];
            bd[j] = ok ? gm[j] : bd[j];
            gb[j] = ok ? g : gb[j];
        }
    }

    // epilogue: NO per-segment index recovery. Rare too-close fallback
    // rescans with the filter and resolves its exact local index (flag=1).
#pragma unroll
    for (int j = 0; j < QT; j++) {
        int loc = gb[j] << 4;            // group base (finalize scans 16)
        unsigned flag = 0u;
        float tmin = MIN_T2 - qc2[j];
        if (bd[j] < tmin) {
            float fb = __builtin_inff(); int fi = 0;
            for (int i = 0; i < segn; i++) {
                float4 c = lds[(i >> 4) * GSTRIDE + (i & (G - 1))];
                float e = edot(c, qx[j], qy[j], qz[j]);
                bool ok = (e >= tmin) && (e < fb);
                fb = ok ? e : fb;
                fi = ok ? i : fi;
            }
            bd[j] = fb; loc = fi; flag = 1u;
        }
        int q = b * MM + m0 + j * TPB;
        unsigned long long key =
            ((unsigned long long)emap(bd[j]) << 32) |
            ((unsigned)seg << 15) | ((unsigned)loc << 8) | (flag << 7);
        partials[(size_t)seg * NQ + q] = key;
    }
}

// Kernel 2: per-query u64-min (seg-split as R11), then ONE deferred index
// recovery per query: decode (e, seg, loc, flag); if flag=0, equality-scan
// the winning group's 16 candidates recomputed from vt/valid via the
// SHARED helpers (bit-exact vs nn's scan). Pads: address clamped to NN-1,
// e predicated to +inf (downward override -> real slots win). flag=1: loc
// is already the exact local index. d2 = tgt + qc2 (same op as before).
__global__ __launch_bounds__(128) void finalize_kernel(
    const unsigned long long* __restrict__ partials,
    const float* __restrict__ cloth, const float* __restrict__ vt,
    const int* __restrict__ valid,
    const int* __restrict__ smpl_idx, const float* __restrict__ sdf,
    const int* __restrict__ cloth_idx, const float* __restrict__ sdf_thresh,
    const float* __restrict__ dist_thresh,
    float* __restrict__ bsum, int* __restrict__ bmatch)
{
    int lq   = threadIdx.x & 63;
    int half = threadIdx.x >> 6;              // 0 or 1 (wave-uniform)
    int q = blockIdx.x * 64 + lq;             // 512 blocks x 64 queries
    int b = q >> 13;
    int s0 = half * 32;
    unsigned long long mm[8];
#pragma unroll
    for (int k = 0; k < 8; k++) mm[k] = ~0ULL;
#pragma unroll
    for (int s = 0; s < 32; s += 8) {
#pragma unroll
        for (int k = 0; k < 8; k++)
            mm[k] = u64min(mm[k], partials[(size_t)(s0 + s + k) * NQ + q]);
    }
    unsigned long long key =
        u64min(u64min(u64min(mm[0], mm[1]), u64min(mm[2], mm[3])),
               u64min(u64min(mm[4], mm[5]), u64min(mm[6], mm[7])));

    __shared__ unsigned long long lk[64];
    if (half == 1) lk[lq] = key;
    __syncthreads();
    if (half == 0) {
        key = u64min(key, lk[lq]);

        unsigned em = (unsigned)(key >> 32);
        unsigned lw = (unsigned)key;
        int seg  = (int)((lw >> 15) & 63u);
        int loc  = (int)((lw >> 8) & 127u);
        int flag = (int)((lw >> 7) & 1u);
        // inverse of emap
        unsigned tb2 = (em & 0x80000000u) ? (em ^ 0x80000000u) : ~em;
        float tgt = __uint_as_float(tb2);

        int n0   = seg * SEGN;
        int segn = (NN - n0 < SEGN) ? (NN - n0) : SEGN;
        int qm = q & (MM - 1);
        const float* qp = cloth + ((size_t)b * MM + qm) * 3;
        float qx = qp[0], qy = qp[1], qz = qp[2];
        float qc2 = qx * qx + qy * qy + qz * qz;
        const float* vtb    = vt + (size_t)b * NN * 3;
        const int*   validb = valid + b * NN;

        int tloc = 0;
        if (!flag) {
            // downward override -> lowest matching t; all 16 loads
            // independent and in flight (L2-resident: vt+valid ~440KB)
#pragma unroll
            for (int t = G - 1; t >= 0; --t) {
                int n  = n0 + loc + t;
                int nc = (n < NN) ? n : (NN - 1);      // safe address
                float4 c = prep_cand(vtb, validb, nc);
                float e = ((loc + t) < segn) ? edot(c, qx, qy, qz)
                                             : __builtin_inff();
                tloc = (e == tgt) ? t : tloc;
            }
        }
        int idx = n0 + loc + tloc;                     // flag=1 -> tloc=0

        float d2v = tgt + qc2;
        int target = smpl_idx[b * NN + idx];
        int ci0 = cloth_idx[0], ci1 = cloth_idx[1];
        bool match = (target == ci0) || (target == ci1);
        bool near_ = sqrtf(d2v) < dist_thresh[0];      // inf -> false
        float s = sdf[q];
        float contrib = near_ ? (match ? fabsf(s) : fabsf(s - sdf_thresh[0]))
                              : 0.0f;
        int mt = match ? 1 : 0;

        for (int off = 32; off > 0; off >>= 1) {
            contrib += __shfl_down(contrib, off, 64);
            mt      |= __shfl_down(mt, off, 64);
        }
        if (lq == 0) {
            bsum[blockIdx.x]   = contrib;
            bmatch[blockIdx.x] = mt;
        }
    }
}

// Kernel 3: 512 block-partials -> 4 batch losses. Wave w reduces partials
// [64w,64w+64) (all one batch); pairs of wave sums combine via LDS.
__global__ __launch_bounds__(512) void reduce_kernel(
    const float* __restrict__ bs, const int* __restrict__ bm,
    float* __restrict__ out)
{
    int t = threadIdx.x;          // 0..511
    float s = bs[t];
    int   m = bm[t];
    for (int off = 32; off > 0; off >>= 1) {
        s += __shfl_down(s, off, 64);
        m |= __shfl_down(m, off, 64);
    }
    __shared__ float wsu[8];
    __shared__ int   wma[8];
    int w = t >> 6;
    if ((t & 63) == 0) { wsu[w] = s; wma[w] = m; }
    __syncthreads();
    if (t < BB) {
        float sb = wsu[2 * t] + wsu[2 * t + 1];
        int   mb = wma[2 * t] | wma[2 * t + 1];
        out[t] = sb * (1.0f / (float)MM) * (mb ? 1.0f : 0.0f);
    }
}

extern "C" void kernel_launch(void* const* d_in, const int* in_sizes, int n_in,
                              void* d_out, int out_size, void* d_ws, size_t ws_size,
                              hipStream_t stream)
{
    const float* sdf         = (const float*)d_in[0];
    const float* cloth       = (const float*)d_in[1];
    const int*   smpl_idx    = (const int*)d_in[2];
    const int*   valid       = (const int*)d_in[3];
    const int*   cloth_idx   = (const int*)d_in[4];
    const float* sdf_thresh  = (const float*)d_in[5];
    const float* dist_thresh = (const float*)d_in[6];
    const float* vt          = (const float*)d_in[7];

    char* ws = (char*)d_ws;
    unsigned long long* partials = (unsigned long long*)ws;
    float* bsum   = (float*)(ws + OFF_BSUM);
    int*   bmatch = (int*)(ws + OFF_BMATCH);

    nn_kernel<<<BB * CHUNKS * NSEG, TPB, 0, stream>>>(cloth, vt, valid, partials);
    finalize_kernel<<<NFBLK, 128, 0, stream>>>(
        partials, cloth, vt, valid, smpl_idx, sdf, cloth_idx, sdf_thresh,
        dist_thresh, bsum, bmatch);
    reduce_kernel<<<1, 512, 0, stream>>>(bsum, bmatch, (float*)d_out);
}